// Round 7
// baseline (2041.696 us; speedup 1.0000x reference)
//
#include <hip/hip_runtime.h>

#define N_INT 16384
#define NPTS  20480
#define DIMX  3
#define NRES  8
#define NFC   3
#define DD    128
#define Q     8            // points per wave
#define WPW   4            // waves per workgroup
#define TPB   (WPW*64)
#define TILES_PER_DIM (NPTS/Q)   // 2560
#define INT_TILES     (N_INT/Q)  // 2048 -> tiles >= this are boundary-only

// 16 FMAs: one k-octet (xa=rows k..k+3, xb=rows k+4..k+7) against 8 W rows
#define JET16(acc, xa, xb, WB) do { \
  acc[0]=fmaf(xa.x,WB[0].x,acc[0]); acc[1]=fmaf(xa.x,WB[0].y,acc[1]); \
  acc[0]=fmaf(xa.y,WB[1].x,acc[0]); acc[1]=fmaf(xa.y,WB[1].y,acc[1]); \
  acc[0]=fmaf(xa.z,WB[2].x,acc[0]); acc[1]=fmaf(xa.z,WB[2].y,acc[1]); \
  acc[0]=fmaf(xa.w,WB[3].x,acc[0]); acc[1]=fmaf(xa.w,WB[3].y,acc[1]); \
  acc[0]=fmaf(xb.x,WB[4].x,acc[0]); acc[1]=fmaf(xb.x,WB[4].y,acc[1]); \
  acc[0]=fmaf(xb.y,WB[5].x,acc[0]); acc[1]=fmaf(xb.y,WB[5].y,acc[1]); \
  acc[0]=fmaf(xb.z,WB[6].x,acc[0]); acc[1]=fmaf(xb.z,WB[6].y,acc[1]); \
  acc[0]=fmaf(xb.w,WB[7].x,acc[0]); acc[1]=fmaf(xb.w,WB[7].y,acc[1]); \
} while(0)

// prefetch 8 consecutive W rows (this lane's 2 output features) into WB
#define PREF(WB, KROW) do { \
  const float* wr_ = WL + (size_t)(KROW)*DD + d0; \
  _Pragma("unroll") \
  for (int j_=0;j_<8;++j_) WB[j_] = *(const float2*)(wr_ + j_*DD); \
} while(0)

__device__ __forceinline__ float rlane(float x, int l) {
    return __int_as_float(__builtin_amdgcn_readlane(__float_as_int(x), l));
}

// interior: one octet of k-rows. v,d1 jets from LDS; d2 jet via readlane.
#define OCTET(KOFF, WB) do { \
  const int ls_ = (KOFF) >> 1; \
  _Pragma("unroll") \
  for (int q_=0;q_<Q;++q_) { \
    const float4 x0a=*(const float4*)&A[(q_*2+0)*DD+(KOFF)]; \
    const float4 x0b=*(const float4*)&A[(q_*2+0)*DD+(KOFF)+4]; \
    const float4 x1a=*(const float4*)&A[(q_*2+1)*DD+(KOFF)]; \
    const float4 x1b=*(const float4*)&A[(q_*2+1)*DD+(KOFF)+4]; \
    JET16(av[q_],  x0a,x0b,WB); \
    JET16(ad1[q_], x1a,x1b,WB); \
    const float a0_=rlane(cdd[q_][0], ls_),   a1_=rlane(cdd[q_][1], ls_); \
    const float a2_=rlane(cdd[q_][0], ls_+1), a3_=rlane(cdd[q_][1], ls_+1); \
    const float a4_=rlane(cdd[q_][0], ls_+2), a5_=rlane(cdd[q_][1], ls_+2); \
    const float a6_=rlane(cdd[q_][0], ls_+3), a7_=rlane(cdd[q_][1], ls_+3); \
    ad2[q_][0]=fmaf(a0_,WB[0].x,ad2[q_][0]); ad2[q_][1]=fmaf(a0_,WB[0].y,ad2[q_][1]); \
    ad2[q_][0]=fmaf(a1_,WB[1].x,ad2[q_][0]); ad2[q_][1]=fmaf(a1_,WB[1].y,ad2[q_][1]); \
    ad2[q_][0]=fmaf(a2_,WB[2].x,ad2[q_][0]); ad2[q_][1]=fmaf(a2_,WB[2].y,ad2[q_][1]); \
    ad2[q_][0]=fmaf(a3_,WB[3].x,ad2[q_][0]); ad2[q_][1]=fmaf(a3_,WB[3].y,ad2[q_][1]); \
    ad2[q_][0]=fmaf(a4_,WB[4].x,ad2[q_][0]); ad2[q_][1]=fmaf(a4_,WB[4].y,ad2[q_][1]); \
    ad2[q_][0]=fmaf(a5_,WB[5].x,ad2[q_][0]); ad2[q_][1]=fmaf(a5_,WB[5].y,ad2[q_][1]); \
    ad2[q_][0]=fmaf(a6_,WB[6].x,ad2[q_][0]); ad2[q_][1]=fmaf(a6_,WB[6].y,ad2[q_][1]); \
    ad2[q_][0]=fmaf(a7_,WB[7].x,ad2[q_][0]); ad2[q_][1]=fmaf(a7_,WB[7].y,ad2[q_][1]); \
  } \
} while(0)

// boundary: value jet only
#define OCTL(KOFF, WB) do { \
  _Pragma("unroll") \
  for (int q_=0;q_<Q;++q_) { \
    const float4 x0a=*(const float4*)&A[q_*DD+(KOFF)]; \
    const float4 x0b=*(const float4*)&A[q_*DD+(KOFF)+4]; \
    JET16(av[q_], x0a,x0b,WB); \
  } \
} while(0)

__global__ __launch_bounds__(TPB, 2) void pinn_main(
    const float* __restrict__ X,
    const float* __restrict__ w_first,
    const float* __restrict__ b_first,
    const float* __restrict__ W_res,
    const float* __restrict__ b_res,
    const float* __restrict__ W_last,
    const float* __restrict__ b_last,
    const float* __restrict__ lb,
    const float* __restrict__ ub,
    float* __restrict__ Fout,
    float* __restrict__ F2out)
{
    __shared__ float ldsA[WPW][2*Q*DD];   // 4 x 8 KB, wave-private; jets v,d1 only
    const int wave = threadIdx.x >> 6;
    const int lane = threadIdx.x & 63;
    const int gw   = blockIdx.x * WPW + wave;
    const int dim  = gw / TILES_PER_DIM;
    const int tile = gw % TILES_PER_DIM;
    const int p0   = tile * Q;
    const int d0   = lane * 2;            // this lane owns features d0, d0+1

    float* A = &ldsA[wave][0];

    const float lo = lb[dim], hi = ub[dim];
    const float sc = 2.0f / (hi - lo);
    const float wf0 = w_first[dim*DD + d0];
    const float wf1 = w_first[dim*DD + d0 + 1];
    const float bf0 = b_first[dim*DD + d0];
    const float bf1 = b_first[dim*DD + d0 + 1];

    const float* Wp0 = W_res + (size_t)dim*(NRES*NFC*DD*DD);
    const float* bp0 = b_res + (size_t)dim*(NRES*NFC*DD);
    const float wl0 = W_last[dim*DD + d0];
    const float wl1 = W_last[dim*DD + d0 + 1];
    const float blv = b_last[dim];

    if (tile < INT_TILES) {
        // ================= interior: full 2nd-order jet =================
        float hv[Q][2], hd[Q][2], hdd[Q][2];
#pragma unroll
        for (int q = 0; q < Q; ++q) {
            float x = X[(p0 + q)*DIMX + dim];
            float t = fmaf(x - lo, sc, -1.0f);
            hv[q][0] = fmaf(t, wf0, bf0);
            hv[q][1] = fmaf(t, wf1, bf1);
            hd[q][0] = sc*wf0;
            hd[q][1] = sc*wf1;
            hdd[q][0] = 0.f; hdd[q][1] = 0.f;
        }

        const float* Wp = Wp0;
        const float* bp = bp0;

#pragma unroll 1
        for (int r = 0; r < NRES; ++r) {
            // current d2-jet stays in registers (readlane-broadcast instead of LDS)
            float cdd[Q][2];
#pragma unroll
            for (int q = 0; q < Q; ++q) { cdd[q][0] = hdd[q][0]; cdd[q][1] = hdd[q][1]; }

            // stage v, d1 jets into this wave's LDS region (layer-0 input)
#pragma unroll
            for (int q = 0; q < Q; ++q) {
                *(float2*)&A[(q*2+0)*DD + d0] = make_float2(hv[q][0], hv[q][1]);
                *(float2*)&A[(q*2+1)*DD + d0] = make_float2(hd[q][0], hd[q][1]);
            }

#pragma unroll 1
            for (int l = 0; l < NFC; ++l) {
                float av[Q][2] = {}, ad1[Q][2] = {}, ad2[Q][2] = {};
                const float* WL = Wp;
                float2 wba[8], wbb[8];
                PREF(wba, 0);
#pragma unroll 1
                for (int k0 = 0; k0 < DD; k0 += 16) {
                    PREF(wbb, k0+8);
                    OCTET(k0, wba);
                    if (k0 + 16 < DD) PREF(wba, k0+16);
                    OCTET(k0+8, wbb);
                }
                // bias (value jet only)
                const float bv0 = bp[d0], bv1 = bp[d0+1];
#pragma unroll
                for (int q = 0; q < Q; ++q) { av[q][0] += bv0; av[q][1] += bv1; }

                if (l < NFC-1) {
                    // g = sin(a) jet: v,d1 -> LDS ; d2 -> registers
#pragma unroll
                    for (int q = 0; q < Q; ++q) {
                        float nv[2], nd[2];
#pragma unroll
                        for (int i = 0; i < 2; ++i) {
                            float s = __sinf(av[q][i]);
                            float c = __cosf(av[q][i]);
                            nv[i]  = s;
                            cdd[q][i] = fmaf(c, ad2[q][i], -s*ad1[q][i]*ad1[q][i]);
                            nd[i]  = c*ad1[q][i];
                        }
                        *(float2*)&A[(q*2+0)*DD + d0] = make_float2(nv[0], nv[1]);
                        *(float2*)&A[(q*2+1)*DD + d0] = make_float2(nd[0], nd[1]);
                    }
                } else {
                    // h = sin(a + h) jet (residual), stays in registers
#pragma unroll
                    for (int q = 0; q < Q; ++q) {
#pragma unroll
                        for (int i = 0; i < 2; ++i) {
                            float zu = av[q][i]  + hv[q][i];
                            float z1 = ad1[q][i] + hd[q][i];
                            float z2 = ad2[q][i] + hdd[q][i];
                            float s = __sinf(zu);
                            float c = __cosf(zu);
                            hv[q][i]  = s;
                            hd[q][i]  = c*z1;
                            hdd[q][i] = fmaf(c, z2, -s*z1*z1);
                        }
                    }
                }
                Wp += DD*DD;
                bp += DD;
            }
        }

#pragma unroll
        for (int q = 0; q < Q; ++q) {
            float pv = fmaf(hv[q][0],  wl0, hv[q][1]*wl1);
            float p2 = fmaf(hdd[q][0], wl0, hdd[q][1]*wl1);
#pragma unroll
            for (int off = 32; off > 0; off >>= 1) {
                pv += __shfl_down(pv, off);
                p2 += __shfl_down(p2, off);
            }
            if (lane == 0) {
                Fout[dim*NPTS + p0 + q]  = pv + blv;
                F2out[dim*NPTS + p0 + q] = p2;
            }
        }
    } else {
        // ================= boundary: value only (1/3 work) =================
        float hv[Q][2];
#pragma unroll
        for (int q = 0; q < Q; ++q) {
            float x = X[(p0 + q)*DIMX + dim];
            float t = fmaf(x - lo, sc, -1.0f);
            hv[q][0] = fmaf(t, wf0, bf0);
            hv[q][1] = fmaf(t, wf1, bf1);
        }

        const float* Wp = Wp0;
        const float* bp = bp0;

#pragma unroll 1
        for (int r = 0; r < NRES; ++r) {
#pragma unroll
            for (int q = 0; q < Q; ++q)
                *(float2*)&A[q*DD + d0] = make_float2(hv[q][0], hv[q][1]);

#pragma unroll 1
            for (int l = 0; l < NFC; ++l) {
                float av[Q][2] = {};
                const float* WL = Wp;
                float2 wba[8], wbb[8];
                PREF(wba, 0);
#pragma unroll 1
                for (int k0 = 0; k0 < DD; k0 += 16) {
                    PREF(wbb, k0+8);
                    OCTL(k0, wba);
                    if (k0 + 16 < DD) PREF(wba, k0+16);
                    OCTL(k0+8, wbb);
                }
                const float bv0 = bp[d0], bv1 = bp[d0+1];
#pragma unroll
                for (int q = 0; q < Q; ++q) { av[q][0] += bv0; av[q][1] += bv1; }

                if (l < NFC-1) {
#pragma unroll
                    for (int q = 0; q < Q; ++q)
                        *(float2*)&A[q*DD + d0] =
                            make_float2(__sinf(av[q][0]), __sinf(av[q][1]));
                } else {
#pragma unroll
                    for (int q = 0; q < Q; ++q) {
                        hv[q][0] = __sinf(av[q][0] + hv[q][0]);
                        hv[q][1] = __sinf(av[q][1] + hv[q][1]);
                    }
                }
                Wp += DD*DD;
                bp += DD;
            }
        }

#pragma unroll
        for (int q = 0; q < Q; ++q) {
            float pv = fmaf(hv[q][0], wl0, hv[q][1]*wl1);
#pragma unroll
            for (int off = 32; off > 0; off >>= 1)
                pv += __shfl_down(pv, off);
            if (lane == 0)
                Fout[dim*NPTS + p0 + q] = pv + blv;
        }
    }
}

__global__ void pinn_combine(const float* __restrict__ F, const float* __restrict__ F2,
                             const float* __restrict__ rhs, float* __restrict__ out)
{
    int n = blockIdx.x*256 + threadIdx.x;
    if (n >= NPTS) return;
    float f0 = F[n], f1 = F[NPTS+n], f2 = F[2*NPTS+n];
    if (n < N_INT) {
        float lap = F2[n]*f1*f2 + F2[NPTS+n]*f0*f2 + F2[2*NPTS+n]*f0*f1;
        out[n] = -lap - rhs[n];
    } else {
        out[n] = f0*f1*f2 - rhs[n];
    }
}

extern "C" void kernel_launch(void* const* d_in, const int* in_sizes, int n_in,
                              void* d_out, int out_size, void* d_ws, size_t ws_size,
                              hipStream_t stream) {
    const float* X       = (const float*)d_in[0];
    const float* rhs     = (const float*)d_in[1];
    const float* w_first = (const float*)d_in[2];
    const float* b_first = (const float*)d_in[3];
    const float* W_res   = (const float*)d_in[4];
    const float* b_res   = (const float*)d_in[5];
    const float* W_last  = (const float*)d_in[6];
    const float* b_last  = (const float*)d_in[7];
    const float* lbv     = (const float*)d_in[8];
    const float* ubv     = (const float*)d_in[9];
    float* out = (float*)d_out;

    float* F  = (float*)d_ws;            // [3][NPTS]
    float* F2 = F + 3*NPTS;              // [3][NPTS]

    int wgs = DIMX * TILES_PER_DIM / WPW; // 1920
    pinn_main<<<wgs, TPB, 0, stream>>>(X, w_first, b_first, W_res, b_res,
                                       W_last, b_last, lbv, ubv, F, F2);
    pinn_combine<<<(NPTS+255)/256, 256, 0, stream>>>(F, F2, rhs, out);
}

// Round 8
// 1779.144 us; speedup vs baseline: 1.1476x; 1.1476x over previous
//
#include <hip/hip_runtime.h>

#define N_INT 16384
#define NPTS  20480
#define DIMX  3
#define NRES  8
#define NFC   3
#define DD    128
#define Q     8            // points per wave
#define WPW   4            // waves per workgroup
#define TPB   (WPW*64)
#define TILES_PER_DIM (NPTS/Q)   // 2560
#define INT_TILES     (N_INT/Q)  // 2048 -> tiles >= this are boundary-only

typedef float v2f __attribute__((ext_vector_type(2)));
typedef float v4f __attribute__((ext_vector_type(4)));

// packed fma: ACC(pair of 2 output features) += W2(pair) * broadcast(lo/hi half of X2)
// op_sel semantics: lo result half uses op_sel[i] half of src i; hi result uses op_sel_hi[i].
#define PKFMA_LO(ACC, W2, X2) \
  asm("v_pk_fma_f32 %0, %1, %2, %0 op_sel:[0,0,0] op_sel_hi:[1,0,1]" \
      : "+v"(ACC) : "v"(W2), "v"(X2))
#define PKFMA_HI(ACC, W2, X2) \
  asm("v_pk_fma_f32 %0, %1, %2, %0 op_sel:[0,1,0] op_sel_hi:[1,1,1]" \
      : "+v"(ACC) : "v"(W2), "v"(X2))

__device__ __forceinline__ float rlane(float x, int l) {
    return __int_as_float(__builtin_amdgcn_readlane(__float_as_int(x), l));
}

__global__ __launch_bounds__(TPB, 2) void pinn_main(
    const float* __restrict__ X,
    const float* __restrict__ w_first,
    const float* __restrict__ b_first,
    const float* __restrict__ W_res,
    const float* __restrict__ b_res,
    const float* __restrict__ W_last,
    const float* __restrict__ b_last,
    const float* __restrict__ lb,
    const float* __restrict__ ub,
    float* __restrict__ Fout,
    float* __restrict__ F2out)
{
    __shared__ float ldsA[WPW][2*Q*DD];   // 4 x 8 KB, wave-private; jets v,d1 only
    const int wave = threadIdx.x >> 6;
    const int lane = threadIdx.x & 63;
    const int gw   = blockIdx.x * WPW + wave;
    const int dim  = gw / TILES_PER_DIM;
    const int tile = gw % TILES_PER_DIM;
    const int p0   = tile * Q;
    const int d0   = lane * 2;            // this lane owns features d0, d0+1

    float* A = &ldsA[wave][0];

    const float lo = lb[dim], hi = ub[dim];
    const float sc = 2.0f / (hi - lo);
    const float wf0 = w_first[dim*DD + d0];
    const float wf1 = w_first[dim*DD + d0 + 1];
    const float bf0 = b_first[dim*DD + d0];
    const float bf1 = b_first[dim*DD + d0 + 1];

    const float* Wp0 = W_res + (size_t)dim*(NRES*NFC*DD*DD);
    const float* bp0 = b_res + (size_t)dim*(NRES*NFC*DD);
    const float wl0 = W_last[dim*DD + d0];
    const float wl1 = W_last[dim*DD + d0 + 1];
    const float blv = b_last[dim];

    if (tile < INT_TILES) {
        // ================= interior: full 2nd-order jet =================
        float hv[Q][2], hd[Q][2], hdd[Q][2];
#pragma unroll
        for (int q = 0; q < Q; ++q) {
            float x = X[(p0 + q)*DIMX + dim];
            float t = fmaf(x - lo, sc, -1.0f);
            hv[q][0] = fmaf(t, wf0, bf0);
            hv[q][1] = fmaf(t, wf1, bf1);
            hd[q][0] = sc*wf0;
            hd[q][1] = sc*wf1;
            hdd[q][0] = 0.f; hdd[q][1] = 0.f;
        }

        const float* Wp = Wp0;
        const float* bp = bp0;

#pragma unroll 1
        for (int r = 0; r < NRES; ++r) {
            // current d2-jet stays in registers (readlane-broadcast instead of LDS)
            float cdd[Q][2];
#pragma unroll
            for (int q = 0; q < Q; ++q) { cdd[q][0] = hdd[q][0]; cdd[q][1] = hdd[q][1]; }

            // stage v, d1 jets into this wave's LDS region (layer-0 input)
#pragma unroll
            for (int q = 0; q < Q; ++q) {
                *(float2*)&A[(q*2+0)*DD + d0] = make_float2(hv[q][0], hv[q][1]);
                *(float2*)&A[(q*2+1)*DD + d0] = make_float2(hd[q][0], hd[q][1]);
            }

#pragma unroll 1
            for (int l = 0; l < NFC; ++l) {
                v2f av[Q], ad1[Q];
                float ad2[Q][2];
#pragma unroll
                for (int q = 0; q < Q; ++q) {
                    av[q]  = (v2f){0.f, 0.f};
                    ad1[q] = (v2f){0.f, 0.f};
                    ad2[q][0] = 0.f; ad2[q][1] = 0.f;
                }
                const float* WL = Wp;
#pragma unroll 1
                for (int k0 = 0; k0 < DD; k0 += 4) {
                    const float* wr = WL + k0*DD + d0;
                    const v2f w0 = *(const v2f*)(wr);
                    const v2f w1 = *(const v2f*)(wr + DD);
                    const v2f w2 = *(const v2f*)(wr + 2*DD);
                    const v2f w3 = *(const v2f*)(wr + 3*DD);
                    const int ls = k0 >> 1;   // uniform: SGPR lane index
#pragma unroll
                    for (int q = 0; q < Q; ++q) {
                        const v4f x0 = *(const v4f*)&A[(q*2+0)*DD + k0];
                        const v4f x1 = *(const v4f*)&A[(q*2+1)*DD + k0];
                        const v2f x0a = x0.lo, x0b = x0.hi;
                        const v2f x1a = x1.lo, x1b = x1.hi;
                        PKFMA_LO(av[q],  w0, x0a);   // += w0 * x0.x
                        PKFMA_HI(av[q],  w1, x0a);   // += w1 * x0.y
                        PKFMA_LO(av[q],  w2, x0b);   // += w2 * x0.z
                        PKFMA_HI(av[q],  w3, x0b);   // += w3 * x0.w
                        PKFMA_LO(ad1[q], w0, x1a);
                        PKFMA_HI(ad1[q], w1, x1a);
                        PKFMA_LO(ad1[q], w2, x1b);
                        PKFMA_HI(ad1[q], w3, x1b);
                        // d2-jet broadcast from registers via readlane (SGPR)
                        const float a0 = rlane(cdd[q][0], ls);
                        const float a1 = rlane(cdd[q][1], ls);
                        const float a2 = rlane(cdd[q][0], ls + 1);
                        const float a3 = rlane(cdd[q][1], ls + 1);
                        ad2[q][0] = fmaf(a0, w0.x, ad2[q][0]);
                        ad2[q][1] = fmaf(a0, w0.y, ad2[q][1]);
                        ad2[q][0] = fmaf(a1, w1.x, ad2[q][0]);
                        ad2[q][1] = fmaf(a1, w1.y, ad2[q][1]);
                        ad2[q][0] = fmaf(a2, w2.x, ad2[q][0]);
                        ad2[q][1] = fmaf(a2, w2.y, ad2[q][1]);
                        ad2[q][0] = fmaf(a3, w3.x, ad2[q][0]);
                        ad2[q][1] = fmaf(a3, w3.y, ad2[q][1]);
                    }
                }
                // bias (value jet only)
                const float bv0 = bp[d0], bv1 = bp[d0+1];
#pragma unroll
                for (int q = 0; q < Q; ++q) av[q] += (v2f){bv0, bv1};

                if (l < NFC-1) {
                    // g = sin(a) jet: v,d1 -> LDS ; d2 -> registers
#pragma unroll
                    for (int q = 0; q < Q; ++q) {
                        const float avq[2]  = {av[q].x,  av[q].y};
                        const float ad1q[2] = {ad1[q].x, ad1[q].y};
                        float nv[2], nd[2];
#pragma unroll
                        for (int i = 0; i < 2; ++i) {
                            float s = __sinf(avq[i]);
                            float c = __cosf(avq[i]);
                            nv[i]  = s;
                            cdd[q][i] = fmaf(c, ad2[q][i], -s*ad1q[i]*ad1q[i]);
                            nd[i]  = c*ad1q[i];
                        }
                        *(float2*)&A[(q*2+0)*DD + d0] = make_float2(nv[0], nv[1]);
                        *(float2*)&A[(q*2+1)*DD + d0] = make_float2(nd[0], nd[1]);
                    }
                } else {
                    // h = sin(a + h) jet (residual), stays in registers
#pragma unroll
                    for (int q = 0; q < Q; ++q) {
                        const float avq[2]  = {av[q].x,  av[q].y};
                        const float ad1q[2] = {ad1[q].x, ad1[q].y};
#pragma unroll
                        for (int i = 0; i < 2; ++i) {
                            float zu = avq[i]  + hv[q][i];
                            float z1 = ad1q[i] + hd[q][i];
                            float z2 = ad2[q][i] + hdd[q][i];
                            float s = __sinf(zu);
                            float c = __cosf(zu);
                            hv[q][i]  = s;
                            hd[q][i]  = c*z1;
                            hdd[q][i] = fmaf(c, z2, -s*z1*z1);
                        }
                    }
                }
                Wp += DD*DD;
                bp += DD;
            }
        }

#pragma unroll
        for (int q = 0; q < Q; ++q) {
            float pv = fmaf(hv[q][0],  wl0, hv[q][1]*wl1);
            float p2 = fmaf(hdd[q][0], wl0, hdd[q][1]*wl1);
#pragma unroll
            for (int off = 32; off > 0; off >>= 1) {
                pv += __shfl_down(pv, off);
                p2 += __shfl_down(p2, off);
            }
            if (lane == 0) {
                Fout[dim*NPTS + p0 + q]  = pv + blv;
                F2out[dim*NPTS + p0 + q] = p2;
            }
        }
    } else {
        // ================= boundary: value only (1/3 work) =================
        float hv[Q][2];
#pragma unroll
        for (int q = 0; q < Q; ++q) {
            float x = X[(p0 + q)*DIMX + dim];
            float t = fmaf(x - lo, sc, -1.0f);
            hv[q][0] = fmaf(t, wf0, bf0);
            hv[q][1] = fmaf(t, wf1, bf1);
        }

        const float* Wp = Wp0;
        const float* bp = bp0;

#pragma unroll 1
        for (int r = 0; r < NRES; ++r) {
#pragma unroll
            for (int q = 0; q < Q; ++q)
                *(float2*)&A[q*DD + d0] = make_float2(hv[q][0], hv[q][1]);

#pragma unroll 1
            for (int l = 0; l < NFC; ++l) {
                v2f av[Q];
#pragma unroll
                for (int q = 0; q < Q; ++q) av[q] = (v2f){0.f, 0.f};
                const float* WL = Wp;
#pragma unroll 1
                for (int k0 = 0; k0 < DD; k0 += 4) {
                    const float* wr = WL + k0*DD + d0;
                    const v2f w0 = *(const v2f*)(wr);
                    const v2f w1 = *(const v2f*)(wr + DD);
                    const v2f w2 = *(const v2f*)(wr + 2*DD);
                    const v2f w3 = *(const v2f*)(wr + 3*DD);
#pragma unroll
                    for (int q = 0; q < Q; ++q) {
                        const v4f x0 = *(const v4f*)&A[q*DD + k0];
                        const v2f x0a = x0.lo, x0b = x0.hi;
                        PKFMA_LO(av[q], w0, x0a);
                        PKFMA_HI(av[q], w1, x0a);
                        PKFMA_LO(av[q], w2, x0b);
                        PKFMA_HI(av[q], w3, x0b);
                    }
                }
                const float bv0 = bp[d0], bv1 = bp[d0+1];
#pragma unroll
                for (int q = 0; q < Q; ++q) av[q] += (v2f){bv0, bv1};

                if (l < NFC-1) {
#pragma unroll
                    for (int q = 0; q < Q; ++q)
                        *(float2*)&A[q*DD + d0] =
                            make_float2(__sinf(av[q].x), __sinf(av[q].y));
                } else {
#pragma unroll
                    for (int q = 0; q < Q; ++q) {
                        hv[q][0] = __sinf(av[q].x + hv[q][0]);
                        hv[q][1] = __sinf(av[q].y + hv[q][1]);
                    }
                }
                Wp += DD*DD;
                bp += DD;
            }
        }

#pragma unroll
        for (int q = 0; q < Q; ++q) {
            float pv = fmaf(hv[q][0], wl0, hv[q][1]*wl1);
#pragma unroll
            for (int off = 32; off > 0; off >>= 1)
                pv += __shfl_down(pv, off);
            if (lane == 0)
                Fout[dim*NPTS + p0 + q] = pv + blv;
        }
    }
}

__global__ void pinn_combine(const float* __restrict__ F, const float* __restrict__ F2,
                             const float* __restrict__ rhs, float* __restrict__ out)
{
    int n = blockIdx.x*256 + threadIdx.x;
    if (n >= NPTS) return;
    float f0 = F[n], f1 = F[NPTS+n], f2 = F[2*NPTS+n];
    if (n < N_INT) {
        float lap = F2[n]*f1*f2 + F2[NPTS+n]*f0*f2 + F2[2*NPTS+n]*f0*f1;
        out[n] = -lap - rhs[n];
    } else {
        out[n] = f0*f1*f2 - rhs[n];
    }
}

extern "C" void kernel_launch(void* const* d_in, const int* in_sizes, int n_in,
                              void* d_out, int out_size, void* d_ws, size_t ws_size,
                              hipStream_t stream) {
    const float* X       = (const float*)d_in[0];
    const float* rhs     = (const float*)d_in[1];
    const float* w_first = (const float*)d_in[2];
    const float* b_first = (const float*)d_in[3];
    const float* W_res   = (const float*)d_in[4];
    const float* b_res   = (const float*)d_in[5];
    const float* W_last  = (const float*)d_in[6];
    const float* b_last  = (const float*)d_in[7];
    const float* lbv     = (const float*)d_in[8];
    const float* ubv     = (const float*)d_in[9];
    float* out = (float*)d_out;

    float* F  = (float*)d_ws;            // [3][NPTS]
    float* F2 = F + 3*NPTS;              // [3][NPTS]

    int wgs = DIMX * TILES_PER_DIM / WPW; // 1920
    pinn_main<<<wgs, TPB, 0, stream>>>(X, w_first, b_first, W_res, b_res,
                                       W_last, b_last, lbv, ubv, F, F2);
    pinn_combine<<<(NPTS+255)/256, 256, 0, stream>>>(F, F2, rhs, out);
}

// Round 9
// 1011.042 us; speedup vs baseline: 2.0194x; 1.7597x over previous
//
#include <hip/hip_runtime.h>

#define N_INT 16384
#define NPTS  20480
#define DIMX  3
#define NRES  8
#define NFC   3
#define DD    128
#define Q     8            // points per wave
#define WPW   4            // waves per workgroup
#define TPB   (WPW*64)
#define TILES_PER_DIM (NPTS/Q)   // 2560
#define INT_TILES     (N_INT/Q)  // 2048 -> tiles >= this are boundary-only
#define NLAYER (DIMX*NRES*NFC)   // 72
#define MT 2                     // M-tiles (32 rows = q*4+jet, jet3=pad)
#define NT 8                     // N-tiles (128 features)
#define KS 4                     // K-steps  (128 k / 32)

typedef unsigned int   u32;
typedef unsigned short u16;
typedef _Float16 f16;
typedef f16   f16x8 __attribute__((ext_vector_type(8)));
typedef float f32x4 __attribute__((ext_vector_type(4)));
typedef float v2f   __attribute__((ext_vector_type(2)));
typedef float v4f   __attribute__((ext_vector_type(4)));

// ---------- fp32 -> (hi,lo) fp16 split, packed u32 (hi in low16) ----------
__device__ __forceinline__ u32 pack_split(float x) {
    f16 h = (f16)x;
    f16 l = (f16)(x - (float)h);
    union { f16 f; u16 u; } a, b;
    a.f = h; b.f = l;
    return (u32)a.u | ((u32)b.u << 16);
}

// swizzled LDS index for packed-A [row][feat] u32; XOR feat bits3-5 with row
// bits1-3 -> writes <=2-way, frag reads <=2-way bank aliasing (free, m136)
__device__ __forceinline__ int aidx(int row, int feat) {
    return row*DD + (feat ^ (((row >> 1) & 7) << 3));
}

// ---------- boundary-path packed fp32 fma (round-8 proven) ----------
#define PKFMA_LO(ACC, W2, X2) \
  asm("v_pk_fma_f32 %0, %1, %2, %0 op_sel:[0,0,0] op_sel_hi:[1,0,1]" \
      : "+v"(ACC) : "v"(W2), "v"(X2))
#define PKFMA_HI(ACC, W2, X2) \
  asm("v_pk_fma_f32 %0, %1, %2, %0 op_sel:[0,1,0] op_sel_hi:[1,1,1]" \
      : "+v"(ACC) : "v"(W2), "v"(X2))

// ---------- W pre-pack: fragment-ordered fp16 hi/lo ----------
// dst index t = ((L*KS+ks)*NT+nt)*64+lane ; elem i -> W[L][k=ks*32+(lane>>4)*8+i][n=nt*16+(lane&15)]
__global__ void pack_w(const float* __restrict__ W_res,
                       f16* __restrict__ Whi, f16* __restrict__ Wlo)
{
    int t = blockIdx.x*256 + threadIdx.x;
    if (t >= NLAYER*KS*NT*64) return;
    int lane = t & 63;
    int nt   = (t >> 6) & 7;
    int ks   = (t >> 9) & 3;
    int L    = t >> 11;
    int n = nt*16 + (lane & 15);
    size_t src = (size_t)L*DD*DD + (size_t)(ks*32 + (lane >> 4)*8)*DD + n;
    f16x8 vh, vl;
#pragma unroll
    for (int i = 0; i < 8; ++i) {
        float w = W_res[src + (size_t)i*DD];
        f16 hh = (f16)w;
        vh[i] = hh;
        vl[i] = (f16)(w - (float)hh);
    }
    ((f16x8*)Whi)[t] = vh;
    ((f16x8*)Wlo)[t] = vl;
}

__global__ __launch_bounds__(TPB, 2) void pinn_main(
    const float* __restrict__ X,
    const float* __restrict__ w_first,
    const float* __restrict__ b_first,
    const float* __restrict__ W_res,
    const float* __restrict__ b_res,
    const float* __restrict__ W_last,
    const float* __restrict__ b_last,
    const float* __restrict__ lb,
    const float* __restrict__ ub,
    const f16* __restrict__ Whi,
    const f16* __restrict__ Wlo,
    float* __restrict__ Fout,
    float* __restrict__ F2out)
{
    __shared__ u32 ldsA[WPW][32*DD];     // 4 x 16 KB, wave-private
    const int wave = threadIdx.x >> 6;
    const int lane = threadIdx.x & 63;
    const int gw   = blockIdx.x * WPW + wave;
    const int dim  = gw / TILES_PER_DIM;
    const int tile = gw % TILES_PER_DIM;
    const int p0   = tile * Q;

    const float lo = lb[dim], hi = ub[dim];
    const float sc = 2.0f / (hi - lo);
    const float blv = b_last[dim];
    const float* bp0 = b_res + (size_t)dim*(NRES*NFC*DD);

    if (tile < INT_TILES) {
        // ===== interior: full 2nd-order jet via hi/lo-split f16 MFMA =====
        u32* A = ldsA[wave];
        const int g = lane >> 4;          // 0..3 : q-subindex / k-group
        const int c = lane & 15;          // col within 16-tiles
        const f16x8* WHp = (const f16x8*)Whi;
        const f16x8* WLp = (const f16x8*)Wlo;

        // h jets in frag layout: (mt,nt) -> q=4mt+g, feat=16nt+c
        float hv_[MT][NT], hd_[MT][NT], hdd_[MT][NT];
        float wfv[NT], bfv[NT], blw[NT];
        float tq[MT];
#pragma unroll
        for (int mt = 0; mt < MT; ++mt) {
            int q = 4*mt + g;
            float x = X[(p0 + q)*DIMX + dim];
            tq[mt] = fmaf(x - lo, sc, -1.0f);
        }
#pragma unroll
        for (int nt = 0; nt < NT; ++nt) {
            int f = nt*16 + c;
            wfv[nt] = w_first[dim*DD + f];
            bfv[nt] = b_first[dim*DD + f];
            blw[nt] = W_last[dim*DD + f];
        }
#pragma unroll
        for (int mt = 0; mt < MT; ++mt)
#pragma unroll
            for (int nt = 0; nt < NT; ++nt) {
                hv_[mt][nt]  = fmaf(tq[mt], wfv[nt], bfv[nt]);
                hd_[mt][nt]  = sc * wfv[nt];
                hdd_[mt][nt] = 0.f;
            }

        const int Lbase = dim * NRES * NFC;
        const float* bp = bp0;

#pragma unroll 1
        for (int r = 0; r < NRES; ++r) {
            // stage h jets -> A (rows q*4+jet; pad row 3 never written/read)
#pragma unroll
            for (int mt = 0; mt < MT; ++mt)
#pragma unroll
                for (int nt = 0; nt < NT; ++nt) {
                    int row = mt*16 + 4*g;
                    int f   = nt*16 + c;
                    A[aidx(row+0, f)] = pack_split(hv_[mt][nt]);
                    A[aidx(row+1, f)] = pack_split(hd_[mt][nt]);
                    A[aidx(row+2, f)] = pack_split(hdd_[mt][nt]);
                }

#pragma unroll 1
            for (int l = 0; l < NFC; ++l) {
                const int L = Lbase + r*NFC + l;
                f32x4 acc[MT][NT];
#pragma unroll
                for (int mt = 0; mt < MT; ++mt)
#pragma unroll
                    for (int nt = 0; nt < NT; ++nt)
                        acc[mt][nt] = (f32x4){0.f, 0.f, 0.f, 0.f};

#pragma unroll 1
                for (int ks = 0; ks < KS; ++ks) {
                    // A fragments: lane -> row mt*16+c, k = ks*32+g*8 .. +7
                    f16x8 ah[MT], al[MT];
#pragma unroll
                    for (int mt = 0; mt < MT; ++mt) {
                        int idx = aidx(mt*16 + c, ks*32 + g*8);
                        const uint4 A0 = *(const uint4*)&A[idx];
                        const uint4 A1 = *(const uint4*)&A[idx + 4];
                        union { u32 u[4]; f16x8 v; } ch, cl;
                        ch.u[0] = (A0.x & 0xFFFFu) | (A0.y << 16);
                        ch.u[1] = (A0.z & 0xFFFFu) | (A0.w << 16);
                        ch.u[2] = (A1.x & 0xFFFFu) | (A1.y << 16);
                        ch.u[3] = (A1.z & 0xFFFFu) | (A1.w << 16);
                        cl.u[0] = (A0.x >> 16) | (A0.y & 0xFFFF0000u);
                        cl.u[1] = (A0.z >> 16) | (A0.w & 0xFFFF0000u);
                        cl.u[2] = (A1.x >> 16) | (A1.y & 0xFFFF0000u);
                        cl.u[3] = (A1.z >> 16) | (A1.w & 0xFFFF0000u);
                        ah[mt] = ch.v;  al[mt] = cl.v;
                    }
                    const f16x8* whb = WHp + (size_t)((L*KS + ks)*NT)*64;
                    const f16x8* wlb = WLp + (size_t)((L*KS + ks)*NT)*64;
#pragma unroll
                    for (int nt = 0; nt < NT; ++nt) {
                        f16x8 bh = whb[nt*64 + lane];
                        f16x8 bl = wlb[nt*64 + lane];
#pragma unroll
                        for (int mt = 0; mt < MT; ++mt) {
                            acc[mt][nt] = __builtin_amdgcn_mfma_f32_16x16x32_f16(ah[mt], bh, acc[mt][nt], 0, 0, 0);
                            acc[mt][nt] = __builtin_amdgcn_mfma_f32_16x16x32_f16(al[mt], bh, acc[mt][nt], 0, 0, 0);
                            acc[mt][nt] = __builtin_amdgcn_mfma_f32_16x16x32_f16(ah[mt], bl, acc[mt][nt], 0, 0, 0);
                        }
                    }
                }

                float bia[NT];
#pragma unroll
                for (int nt = 0; nt < NT; ++nt) bia[nt] = bp[nt*16 + c];

                if (l < NFC-1) {
                    // g = sin(a) jet -> write A for next layer
#pragma unroll
                    for (int mt = 0; mt < MT; ++mt)
#pragma unroll
                        for (int nt = 0; nt < NT; ++nt) {
                            float a0 = acc[mt][nt][0] + bia[nt];
                            float a1 = acc[mt][nt][1];
                            float a2 = acc[mt][nt][2];
                            float s  = __sinf(a0);
                            float cs = __cosf(a0);
                            float nv  = s;
                            float nd2 = fmaf(cs, a2, -s*a1*a1);
                            float nd1 = cs*a1;
                            int row = mt*16 + 4*g;
                            int f   = nt*16 + c;
                            A[aidx(row+0, f)] = pack_split(nv);
                            A[aidx(row+1, f)] = pack_split(nd1);
                            A[aidx(row+2, f)] = pack_split(nd2);
                        }
                } else {
                    // h = sin(a + h) jet (residual) -> h regs
#pragma unroll
                    for (int mt = 0; mt < MT; ++mt)
#pragma unroll
                        for (int nt = 0; nt < NT; ++nt) {
                            float zu = acc[mt][nt][0] + bia[nt] + hv_[mt][nt];
                            float z1 = acc[mt][nt][1] + hd_[mt][nt];
                            float z2 = acc[mt][nt][2] + hdd_[mt][nt];
                            float s  = __sinf(zu);
                            float cs = __cosf(zu);
                            hv_[mt][nt]  = s;
                            hd_[mt][nt]  = cs*z1;
                            hdd_[mt][nt] = fmaf(cs, z2, -s*z1*z1);
                        }
                }
                bp += DD;
            }
        }

        // ---- head: F = h.Wl + bl ; F2 = h''.Wl ; reduce across c-lanes ----
#pragma unroll
        for (int mt = 0; mt < MT; ++mt) {
            float pv = 0.f, p2 = 0.f;
#pragma unroll
            for (int nt = 0; nt < NT; ++nt) {
                pv = fmaf(hv_[mt][nt],  blw[nt], pv);
                p2 = fmaf(hdd_[mt][nt], blw[nt], p2);
            }
#pragma unroll
            for (int off = 1; off < 16; off <<= 1) {
                pv += __shfl_xor(pv, off);
                p2 += __shfl_xor(p2, off);
            }
            if (c == 0) {
                int q = 4*mt + g;
                Fout [dim*NPTS + p0 + q] = pv + blv;
                F2out[dim*NPTS + p0 + q] = p2;
            }
        }
    } else {
        // ===== boundary: value only (round-8 proven pk path) =====
        float* Af = (float*)ldsA[wave];
        const int d0 = lane * 2;
        const float wf0 = w_first[dim*DD + d0];
        const float wf1 = w_first[dim*DD + d0 + 1];
        const float bf0 = b_first[dim*DD + d0];
        const float bf1 = b_first[dim*DD + d0 + 1];
        const float wl0 = W_last[dim*DD + d0];
        const float wl1 = W_last[dim*DD + d0 + 1];

        float hv[Q][2];
#pragma unroll
        for (int q = 0; q < Q; ++q) {
            float x = X[(p0 + q)*DIMX + dim];
            float t = fmaf(x - lo, sc, -1.0f);
            hv[q][0] = fmaf(t, wf0, bf0);
            hv[q][1] = fmaf(t, wf1, bf1);
        }

        const float* Wp = W_res + (size_t)dim*(NRES*NFC*DD*DD);
        const float* bp = bp0;

#pragma unroll 1
        for (int r = 0; r < NRES; ++r) {
#pragma unroll
            for (int q = 0; q < Q; ++q)
                *(float2*)&Af[q*DD + d0] = make_float2(hv[q][0], hv[q][1]);

#pragma unroll 1
            for (int l = 0; l < NFC; ++l) {
                v2f av[Q];
#pragma unroll
                for (int q = 0; q < Q; ++q) av[q] = (v2f){0.f, 0.f};
                const float* WL = Wp;
#pragma unroll 1
                for (int k0 = 0; k0 < DD; k0 += 4) {
                    const float* wr = WL + k0*DD + d0;
                    const v2f w0 = *(const v2f*)(wr);
                    const v2f w1 = *(const v2f*)(wr + DD);
                    const v2f w2 = *(const v2f*)(wr + 2*DD);
                    const v2f w3 = *(const v2f*)(wr + 3*DD);
#pragma unroll
                    for (int q = 0; q < Q; ++q) {
                        const v4f x0 = *(const v4f*)&Af[q*DD + k0];
                        const v2f x0a = x0.lo, x0b = x0.hi;
                        PKFMA_LO(av[q], w0, x0a);
                        PKFMA_HI(av[q], w1, x0a);
                        PKFMA_LO(av[q], w2, x0b);
                        PKFMA_HI(av[q], w3, x0b);
                    }
                }
                const float bv0 = bp[d0], bv1 = bp[d0+1];
#pragma unroll
                for (int q = 0; q < Q; ++q) av[q] += (v2f){bv0, bv1};

                if (l < NFC-1) {
#pragma unroll
                    for (int q = 0; q < Q; ++q)
                        *(float2*)&Af[q*DD + d0] =
                            make_float2(__sinf(av[q].x), __sinf(av[q].y));
                } else {
#pragma unroll
                    for (int q = 0; q < Q; ++q) {
                        hv[q][0] = __sinf(av[q].x + hv[q][0]);
                        hv[q][1] = __sinf(av[q].y + hv[q][1]);
                    }
                }
                Wp += DD*DD;
                bp += DD;
            }
        }

#pragma unroll
        for (int q = 0; q < Q; ++q) {
            float pv = fmaf(hv[q][0], wl0, hv[q][1]*wl1);
#pragma unroll
            for (int off = 32; off > 0; off >>= 1)
                pv += __shfl_down(pv, off);
            if (lane == 0)
                Fout[dim*NPTS + p0 + q] = pv + blv;
        }
    }
}

__global__ void pinn_combine(const float* __restrict__ F, const float* __restrict__ F2,
                             const float* __restrict__ rhs, float* __restrict__ out)
{
    int n = blockIdx.x*256 + threadIdx.x;
    if (n >= NPTS) return;
    float f0 = F[n], f1 = F[NPTS+n], f2 = F[2*NPTS+n];
    if (n < N_INT) {
        float lap = F2[n]*f1*f2 + F2[NPTS+n]*f0*f2 + F2[2*NPTS+n]*f0*f1;
        out[n] = -lap - rhs[n];
    } else {
        out[n] = f0*f1*f2 - rhs[n];
    }
}

extern "C" void kernel_launch(void* const* d_in, const int* in_sizes, int n_in,
                              void* d_out, int out_size, void* d_ws, size_t ws_size,
                              hipStream_t stream) {
    const float* X       = (const float*)d_in[0];
    const float* rhs     = (const float*)d_in[1];
    const float* w_first = (const float*)d_in[2];
    const float* b_first = (const float*)d_in[3];
    const float* W_res   = (const float*)d_in[4];
    const float* b_res   = (const float*)d_in[5];
    const float* W_last  = (const float*)d_in[6];
    const float* b_last  = (const float*)d_in[7];
    const float* lbv     = (const float*)d_in[8];
    const float* ubv     = (const float*)d_in[9];
    float* out = (float*)d_out;

    float* F  = (float*)d_ws;                        // [3][NPTS]
    float* F2 = F + 3*NPTS;                          // [3][NPTS]
    f16*   Whi = (f16*)((char*)d_ws + (size_t)6*NPTS*4);
    f16*   Wlo = Whi + (size_t)NLAYER*KS*NT*64*8;    // 1,179,648 f16 each

    int wpthreads = NLAYER*KS*NT*64;                 // 147456
    pack_w<<<(wpthreads + 255)/256, 256, 0, stream>>>(W_res, Whi, Wlo);

    int wgs = DIMX * TILES_PER_DIM / WPW;            // 1920
    pinn_main<<<wgs, TPB, 0, stream>>>(X, w_first, b_first, W_res, b_res,
                                       W_last, b_last, lbv, ubv, Whi, Wlo, F, F2);
    pinn_combine<<<(NPTS+255)/256, 256, 0, stream>>>(F, F2, rhs, out);
}